// Round 1
// baseline (145.739 us; speedup 1.0000x reference)
//
#include <hip/hip_runtime.h>

typedef __attribute__((ext_vector_type(4))) float f32x4;
typedef __attribute__((ext_vector_type(8))) short bf16x8;
typedef __attribute__((ext_vector_type(4))) short bf16x4;

#define D 128
#define BM 64

__device__ __forceinline__ unsigned short f2bf(float f){
  union { float f; unsigned int i; } c; c.f = f;
  unsigned int i = c.i;
  i += 0x7fffu + ((i >> 16) & 1u);   // round-to-nearest-even
  return (unsigned short)(i >> 16);
}
__device__ __forceinline__ float bf2f(unsigned short u){
  union { float f; unsigned int i; } c; c.i = ((unsigned int)u) << 16; return c.f;
}
__device__ __forceinline__ float sigmoid_f(float t){
  return 1.0f / (1.0f + __expf(-t));
}
__device__ __forceinline__ float tanh_f(float t){
  t = fminf(fmaxf(t, -20.0f), 20.0f);
  float e = __expf(2.0f * t);
  return (e - 1.0f) / (e + 1.0f);
}

// Pack W[k=256][n=128] fp32 -> bf16 MFMA B-fragments:
// frag f = nf*8+kk ; lane l holds col = nf*16+(l&15), k = kk*32+(l>>4)*8+j (j=0..7)
__global__ void prep_weights(const float* __restrict__ Wr, const float* __restrict__ Wz,
                             const float* __restrict__ Wh, unsigned short* __restrict__ wp)
{
  int w = blockIdx.x >> 6;          // 0:Wr 1:Wz 2:Wh
  int f = blockIdx.x & 63;          // nf*8 + kk
  int l = threadIdx.x;              // 0..63
  const float* src = (w == 0) ? Wr : ((w == 1) ? Wz : Wh);
  int nf = f >> 3, kk = f & 7;
  int col = nf * 16 + (l & 15);
  int k0  = kk * 32 + (l >> 4) * 8;
  unsigned short* dst = wp + w * 32768 + (f * 64 + l) * 8;
#pragma unroll
  for (int j = 0; j < 8; ++j)
    dst[j] = f2bf(src[(k0 + j) * D + col]);
}

__global__ __launch_bounds__(256, 3) void gru_fused(
    const float* __restrict__ x, const float* __restrict__ h,
    const float* __restrict__ brp, const float* __restrict__ bzp, const float* __restrict__ bhp,
    const unsigned short* __restrict__ wp, float* __restrict__ out)
{
  // A1: xh bf16 [64][256] swizzled (32KB). A2: r*h_tan bf16 [64][128] swizzled (16KB).
  // HN overlays everything after stage2: f32 [64][132] (33.8KB <= 48KB).
  __shared__ __align__(16) unsigned char SMEM[BM * 512 + BM * 256];
  unsigned char* A1 = SMEM;
  unsigned char* A2 = SMEM + BM * 512;
  float* HN = (float*)SMEM;

  const int tid = threadIdx.x;
  const int w   = tid >> 6;
  const int l   = tid & 63;
  const int l15 = l & 15;
  const int lq  = l >> 4;
  const size_t row0 = (size_t)blockIdx.x * BM;

  // ---------- phase 1: logmap0(x), logmap0(h) -> A1 bf16 (swizzled) ----------
  {
    const int row = tid >> 2;
    const int q   = tid & 3;
    const f32x4* xr = (const f32x4*)(x + (row0 + row) * D);
    const f32x4* hr = (const f32x4*)(h + (row0 + row) * D);
    f32x4 v[8];
    float ss = 0.f;
#pragma unroll
    for (int j = 0; j < 8; ++j){
      v[j] = xr[j * 4 + q];
      ss += v[j][0]*v[j][0] + v[j][1]*v[j][1] + v[j][2]*v[j][2] + v[j][3]*v[j][3];
    }
    ss += __shfl_xor(ss, 1, 64);
    ss += __shfl_xor(ss, 2, 64);
    float n = sqrtf(ss);
    float s = (n > 1e-20f) ? (0.5f * __logf((1.f + n) / (1.f - n)) / n) : 1.f;
#pragma unroll
    for (int j = 0; j < 8; ++j){
      unsigned int byte = (unsigned)(row * 512 + (4 * j + q) * 8) ^ (unsigned)((row & 7) << 4);
      bf16x4 pk;
      pk[0] = (short)f2bf(v[j][0] * s); pk[1] = (short)f2bf(v[j][1] * s);
      pk[2] = (short)f2bf(v[j][2] * s); pk[3] = (short)f2bf(v[j][3] * s);
      *(bf16x4*)(A1 + byte) = pk;
    }
    ss = 0.f;
#pragma unroll
    for (int j = 0; j < 8; ++j){
      v[j] = hr[j * 4 + q];
      ss += v[j][0]*v[j][0] + v[j][1]*v[j][1] + v[j][2]*v[j][2] + v[j][3]*v[j][3];
    }
    ss += __shfl_xor(ss, 1, 64);
    ss += __shfl_xor(ss, 2, 64);
    n = sqrtf(ss);
    s = (n > 1e-20f) ? (0.5f * __logf((1.f + n) / (1.f - n)) / n) : 1.f;
#pragma unroll
    for (int j = 0; j < 8; ++j){
      unsigned int byte = (unsigned)(row * 512 + 256 + (4 * j + q) * 8) ^ (unsigned)((row & 7) << 4);
      bf16x4 pk;
      pk[0] = (short)f2bf(v[j][0] * s); pk[1] = (short)f2bf(v[j][1] * s);
      pk[2] = (short)f2bf(v[j][2] * s); pk[3] = (short)f2bf(v[j][3] * s);
      *(bf16x4*)(A1 + byte) = pk;
    }
  }
  __syncthreads();

  // ---------- stage 1: wave w computes r,z for cols [w*32, w*32+32) ----------
  const unsigned short* pwr = wp + w * 8192;
  const unsigned short* pwz = wp + 32768 + w * 8192;

  f32x4 accr0[4], accr1[4], accz0[4], accz1[4];
#pragma unroll
  for (int m = 0; m < 4; ++m){ accr0[m] = 0; accr1[m] = 0; accz0[m] = 0; accz1[m] = 0; }

#pragma unroll 2
  for (int kk = 0; kk < 8; ++kk){
    const bf16x8 br0f = *(const bf16x8*)(pwr + kk * 512 + l * 8);
    const bf16x8 br1f = *(const bf16x8*)(pwr + 4096 + kk * 512 + l * 8);
    const bf16x8 bz0f = *(const bf16x8*)(pwz + kk * 512 + l * 8);
    const bf16x8 bz1f = *(const bf16x8*)(pwz + 4096 + kk * 512 + l * 8);
#pragma unroll
    for (int m = 0; m < 4; ++m){
      const int row = m * 16 + l15;
      unsigned int byte = (unsigned)(row * 512 + (kk * 32 + lq * 8) * 2) ^ (unsigned)((row & 7) << 4);
      const bf16x8 a = *(const bf16x8*)(A1 + byte);
      accr0[m] = __builtin_amdgcn_mfma_f32_16x16x32_bf16(a, br0f, accr0[m], 0, 0, 0);
      accr1[m] = __builtin_amdgcn_mfma_f32_16x16x32_bf16(a, br1f, accr1[m], 0, 0, 0);
      accz0[m] = __builtin_amdgcn_mfma_f32_16x16x32_bf16(a, bz0f, accz0[m], 0, 0, 0);
      accz1[m] = __builtin_amdgcn_mfma_f32_16x16x32_bf16(a, bz1f, accz1[m], 0, 0, 0);
    }
  }

  // ---------- epilogue 1: r,z sigmoid; r*h_tan -> A2; z stays in regs ----------
  const int cb = w * 32 + l15;
  const float br0v = brp[cb], br1v = brp[cb + 16];
  const float bz0v = bzp[cb], bz1v = bzp[cb + 16];
  f32x4 zk0[4], zk1[4];
#pragma unroll
  for (int m = 0; m < 4; ++m){
#pragma unroll
    for (int reg = 0; reg < 4; ++reg){
      const int row = m * 16 + lq * 4 + reg;
      const unsigned int swz = (unsigned)((row & 7) << 4);
      {
        float rv = sigmoid_f(accr0[m][reg] + br0v);
        zk0[m][reg] = sigmoid_f(accz0[m][reg] + bz0v);
        float ht = bf2f(*(const unsigned short*)(A1 + ((unsigned)(row * 512 + (128 + cb) * 2) ^ swz)));
        *(unsigned short*)(A2 + ((unsigned)(row * 256 + cb * 2) ^ swz)) = f2bf(rv * ht);
      }
      {
        float rv = sigmoid_f(accr1[m][reg] + br1v);
        zk1[m][reg] = sigmoid_f(accz1[m][reg] + bz1v);
        float ht = bf2f(*(const unsigned short*)(A1 + ((unsigned)(row * 512 + (128 + cb + 16) * 2) ^ swz)));
        *(unsigned short*)(A2 + ((unsigned)(row * 256 + (cb + 16) * 2) ^ swz)) = f2bf(rv * ht);
      }
    }
  }
  __syncthreads();

  // ---------- stage 2: [x_tan | r*h_tan] @ Wh, wave w -> cols [w*32, w*32+32) ----------
  const unsigned short* pwh = wp + 65536 + w * 8192;
  f32x4 ac0[4], ac1[4];
#pragma unroll
  for (int m = 0; m < 4; ++m){ ac0[m] = 0; ac1[m] = 0; }

#pragma unroll 2
  for (int kk = 0; kk < 4; ++kk){
    const bf16x8 b0 = *(const bf16x8*)(pwh + kk * 512 + l * 8);
    const bf16x8 b1 = *(const bf16x8*)(pwh + 4096 + kk * 512 + l * 8);
#pragma unroll
    for (int m = 0; m < 4; ++m){
      const int row = m * 16 + l15;
      unsigned int byte = (unsigned)(row * 512 + (kk * 32 + lq * 8) * 2) ^ (unsigned)((row & 7) << 4);
      const bf16x8 a = *(const bf16x8*)(A1 + byte);
      ac0[m] = __builtin_amdgcn_mfma_f32_16x16x32_bf16(a, b0, ac0[m], 0, 0, 0);
      ac1[m] = __builtin_amdgcn_mfma_f32_16x16x32_bf16(a, b1, ac1[m], 0, 0, 0);
    }
  }
#pragma unroll 2
  for (int kk = 4; kk < 8; ++kk){
    const bf16x8 b0 = *(const bf16x8*)(pwh + kk * 512 + l * 8);
    const bf16x8 b1 = *(const bf16x8*)(pwh + 4096 + kk * 512 + l * 8);
#pragma unroll
    for (int m = 0; m < 4; ++m){
      const int row = m * 16 + l15;
      unsigned int byte = (unsigned)(row * 256 + ((kk - 4) * 32 + lq * 8) * 2) ^ (unsigned)((row & 7) << 4);
      const bf16x8 a = *(const bf16x8*)(A2 + byte);
      ac0[m] = __builtin_amdgcn_mfma_f32_16x16x32_bf16(a, b0, ac0[m], 0, 0, 0);
      ac1[m] = __builtin_amdgcn_mfma_f32_16x16x32_bf16(a, b1, ac1[m], 0, 0, 0);
    }
  }

  // ---------- epilogue 2: h_new_tan in regs ----------
  const float bh0v = bhp[cb], bh1v = bhp[cb + 16];
  f32x4 hn0[4], hn1[4];
#pragma unroll
  for (int m = 0; m < 4; ++m){
#pragma unroll
    for (int reg = 0; reg < 4; ++reg){
      const int row = m * 16 + lq * 4 + reg;
      const unsigned int swz = (unsigned)((row & 7) << 4);
      {
        float htld = tanh_f(ac0[m][reg] + bh0v);
        float ht = bf2f(*(const unsigned short*)(A1 + ((unsigned)(row * 512 + (128 + cb) * 2) ^ swz)));
        float zv = zk0[m][reg];
        hn0[m][reg] = (1.f - zv) * ht + zv * htld;
      }
      {
        float htld = tanh_f(ac1[m][reg] + bh1v);
        float ht = bf2f(*(const unsigned short*)(A1 + ((unsigned)(row * 512 + (128 + cb + 16) * 2) ^ swz)));
        float zv = zk1[m][reg];
        hn1[m][reg] = (1.f - zv) * ht + zv * htld;
      }
    }
  }
  __syncthreads();   // all A1/A2 reads done before HN overlay writes

#pragma unroll
  for (int m = 0; m < 4; ++m){
#pragma unroll
    for (int reg = 0; reg < 4; ++reg){
      const int row = m * 16 + lq * 4 + reg;
      HN[row * 132 + cb]      = hn0[m][reg];
      HN[row * 132 + cb + 16] = hn1[m][reg];
    }
  }
  __syncthreads();

  // ---------- final: expmap0 + proj, coalesced store ----------
  {
    const int row = tid >> 2;
    const int q   = tid & 3;
    f32x4 v[8];
    float ss = 0.f;
#pragma unroll
    for (int j = 0; j < 8; ++j){
      v[j] = *(const f32x4*)(HN + row * 132 + (4 * j + q) * 4);
      ss += v[j][0]*v[j][0] + v[j][1]*v[j][1] + v[j][2]*v[j][2] + v[j][3]*v[j][3];
    }
    ss += __shfl_xor(ss, 1, 64);
    ss += __shfl_xor(ss, 2, 64);
    float n = sqrtf(ss);
    float sc = 1.f;
    if (n > 1e-20f){
      float th = tanh_f(n);
      th = fminf(th, 0.99999f);          // proj: maxnorm = 1 - 1e-5
      sc = th / n;
    }
    f32x4* op = (f32x4*)(out + (row0 + row) * D);
#pragma unroll
    for (int j = 0; j < 8; ++j){
      op[j * 4 + q] = v[j] * sc;
    }
  }
}

extern "C" void kernel_launch(void* const* d_in, const int* in_sizes, int n_in,
                              void* d_out, int out_size, void* d_ws, size_t ws_size,
                              hipStream_t stream)
{
  const float* x   = (const float*)d_in[0];
  const float* h   = (const float*)d_in[1];
  const float* Wr  = (const float*)d_in[2];
  const float* brp = (const float*)d_in[3];
  const float* Wz  = (const float*)d_in[4];
  const float* bzp = (const float*)d_in[5];
  const float* Wh  = (const float*)d_in[6];
  const float* bhp = (const float*)d_in[7];
  unsigned short* wsp = (unsigned short*)d_ws;   // 3 * 32768 bf16 = 192KB packed weights

  prep_weights<<<192, 64, 0, stream>>>(Wr, Wz, Wh, wsp);
  gru_fused<<<262144 / BM, 256, 0, stream>>>(x, h, brp, bzp, bhp, wsp, (float*)d_out);
}